// Round 5
// baseline (650.531 us; speedup 1.0000x reference)
//
#include <hip/hip_runtime.h>
#include <hip/hip_bf16.h>
#include <stdint.h>

// Problem constants
#define NUM_CB   8
#define CB_BITS  11      // id >> 11 = codebook
#define DIM      16
#define HS       2048
#define NTOK     16384

// GEMM tiling: 256x256 tile, BK=64, 8 waves (512 thr), phase-interleaved
#define BM 256
#define BN 256
#define BK 64
#define NKT (HS / BK)    // 32 K-tiles
#define MAXT 72          // sum ceil(cnt_k/256) <= 16384/256 + 8 = 72

// Workspace layout (bytes) — total 134,287,360 < 138,483,712 (known-OK)
#define OFF_CUR    0u
#define OFF_NT     64u
#define OFF_GS     128u
#define OFF_TCB    256u
#define OFF_TROW   1024u
#define OFF_TVAL   2048u
#define OFF_PERM   4096u        // 16384 x u32 -> ends 69632
#define OFF_H      69632u       // 16384*2048 bf16 = 67108864
#define OFF_W2T    67178496u    // 8*2048*2048 bf16 = 67108864
#define WS_NEED    134287360u

typedef __attribute__((ext_vector_type(8))) short s16x8;
typedef __attribute__((ext_vector_type(4))) float f32x4;

__device__ __forceinline__ void load_lds16(const void* g, const void* l) {
    __builtin_amdgcn_global_load_lds(
        (const __attribute__((address_space(1))) uint32_t*)g,
        (__attribute__((address_space(3))) uint32_t*)(void*)(uintptr_t)l, 16, 0, 0);
}

// ---------- planning ----------
extern "C" __global__ void k_countplan(const int* __restrict__ ids,
                                       uint32_t* __restrict__ cur, uint32_t* __restrict__ numT,
                                       uint32_t* __restrict__ tcb, uint32_t* __restrict__ trow,
                                       uint32_t* __restrict__ tval, uint32_t* __restrict__ gstart) {
    __shared__ uint32_t hist[NUM_CB];
    __shared__ uint32_t s_tcb[MAXT], s_trow[MAXT], s_tval[MAXT];
    __shared__ uint32_t s_gs[NUM_CB], s_nt;
    const int tid = threadIdx.x;
    if (tid < NUM_CB) { hist[tid] = 0; cur[tid] = 0; }
    __syncthreads();
    // per-lane register counts (static-indexed), then shfl-reduce per wave
    uint32_t c0=0,c1=0,c2=0,c3=0,c4=0,c5=0,c6=0,c7=0;
    const int4* v4 = (const int4*)ids;
    for (int i = tid; i < NTOK / 4; i += 1024) {
        int4 v = v4[i];
        uint32_t a = (uint32_t)v.x >> CB_BITS, b = (uint32_t)v.y >> CB_BITS;
        uint32_t cc = (uint32_t)v.z >> CB_BITS, d = (uint32_t)v.w >> CB_BITS;
        c0 += (a==0)+(b==0)+(cc==0)+(d==0);  c1 += (a==1)+(b==1)+(cc==1)+(d==1);
        c2 += (a==2)+(b==2)+(cc==2)+(d==2);  c3 += (a==3)+(b==3)+(cc==3)+(d==3);
        c4 += (a==4)+(b==4)+(cc==4)+(d==4);  c5 += (a==5)+(b==5)+(cc==5)+(d==5);
        c6 += (a==6)+(b==6)+(cc==6)+(d==6);  c7 += (a==7)+(b==7)+(cc==7)+(d==7);
    }
    #pragma unroll
    for (int off = 32; off > 0; off >>= 1) {
        c0 += __shfl_down(c0, off); c1 += __shfl_down(c1, off);
        c2 += __shfl_down(c2, off); c3 += __shfl_down(c3, off);
        c4 += __shfl_down(c4, off); c5 += __shfl_down(c5, off);
        c6 += __shfl_down(c6, off); c7 += __shfl_down(c7, off);
    }
    if ((tid & 63) == 0) {
        if (c0) atomicAdd(&hist[0], c0); if (c1) atomicAdd(&hist[1], c1);
        if (c2) atomicAdd(&hist[2], c2); if (c3) atomicAdd(&hist[3], c3);
        if (c4) atomicAdd(&hist[4], c4); if (c5) atomicAdd(&hist[5], c5);
        if (c6) atomicAdd(&hist[6], c6); if (c7) atomicAdd(&hist[7], c7);
    }
    __syncthreads();
    if (tid == 0) {
        uint32_t ps = 0, nt = 0;
        for (int k = 0; k < NUM_CB; ++k) {
            s_gs[k] = ps;
            uint32_t c = hist[k];
            uint32_t tiles = (c + BM - 1) / BM;
            for (uint32_t m = 0; m < tiles; ++m) {
                s_tcb[nt] = (uint32_t)k;
                s_trow[nt] = ps + m * BM;
                uint32_t rem = c - m * BM;
                s_tval[nt] = rem < BM ? rem : BM;
                ++nt;
            }
            ps += c;  // compact rows, no padding
        }
        s_nt = nt;
    }
    __syncthreads();
    const uint32_t nt = s_nt;
    if (tid < MAXT) {
        tcb[tid]  = (tid < (int)nt) ? s_tcb[tid] : 0u;
        trow[tid] = (tid < (int)nt) ? s_trow[tid] : 0u;
        tval[tid] = (tid < (int)nt) ? s_tval[tid] : 0u;
    }
    if (tid < NUM_CB) gstart[tid] = s_gs[tid];
    if (tid == 0) *numT = nt;
}

extern "C" __global__ void k_assign(const int* __restrict__ ids, const uint32_t* __restrict__ gstart,
                                    uint32_t* __restrict__ cur, uint32_t* __restrict__ perm) {
    __shared__ uint32_t lh[NUM_CB], lbase[NUM_CB];
    const int tid = threadIdx.x;
    const int t = blockIdx.x * 256 + tid;
    if (tid < NUM_CB) lh[tid] = 0;
    __syncthreads();
    const int cb = (uint32_t)ids[t] >> CB_BITS;
    atomicAdd(&lh[cb], 1u);
    __syncthreads();
    if (tid < NUM_CB) {
        lbase[tid] = lh[tid] ? atomicAdd(&cur[tid], lh[tid]) : 0u;
        lh[tid] = 0;
    }
    __syncthreads();
    const uint32_t r = atomicAdd(&lh[cb], 1u);
    perm[gstart[cb] + lbase[cb] + r] = (uint32_t)t;
}

// ---------- H build: 256-row tiles, grid (MAXT, 8) ----------
extern "C" __global__ void k_hbuild(const int* __restrict__ ids, const float* __restrict__ emb,
                                    const float* __restrict__ W1, const float* __restrict__ b1,
                                    const uint32_t* __restrict__ numT, const uint32_t* __restrict__ tcb,
                                    const uint32_t* __restrict__ trow, const uint32_t* __restrict__ tval,
                                    const uint32_t* __restrict__ perm, __hip_bfloat16* __restrict__ H) {
    if (blockIdx.x >= *numT) return;
    const int cb = (int)tcb[blockIdx.x];
    const int row0 = (int)trow[blockIdx.x];
    const int valid = (int)tval[blockIdx.x];
    const int col0 = blockIdx.y * 256;
    const int tid = threadIdx.x;

    __shared__ float es[BM][DIM];     // 16 KB
    __shared__ float w1s[DIM][256];   // 16 KB
    __shared__ int   rid[BM];

    rid[tid] = (tid < valid) ? ids[perm[row0 + tid]] : 0;
    __syncthreads();
    #pragma unroll
    for (int i = 0; i < 4; ++i) {                 // 1024 float4 = es
        int idx = i * 256 + tid;
        int r = idx >> 2, q = (idx & 3) * 4;
        *(float4*)&es[r][q] = *(const float4*)&emb[(size_t)rid[r] * DIM + q];
    }
    const float* W1k = W1 + (size_t)cb * DIM * HS + col0;
    #pragma unroll
    for (int i = 0; i < 4; ++i) {                 // 1024 float4 = w1s
        int idx = i * 256 + tid;
        int d = idx >> 6, c4 = (idx & 63) * 4;
        *(float4*)&w1s[d][c4] = *(const float4*)&W1k[(size_t)d * HS + c4];
    }
    __syncthreads();

    float w[DIM];
    #pragma unroll
    for (int d = 0; d < DIM; ++d) w[d] = w1s[d][tid];
    const float bb = b1[(size_t)cb * HS + col0 + tid];
    __hip_bfloat16* Hc = H + (size_t)row0 * HS + col0 + tid;

    for (int r = 0; r < BM; ++r) {
        if (r >= valid) break;
        const float4 e0 = *(const float4*)&es[r][0];
        const float4 e1 = *(const float4*)&es[r][4];
        const float4 e2 = *(const float4*)&es[r][8];
        const float4 e3 = *(const float4*)&es[r][12];
        float acc = bb;
        acc += e0.x*w[0] + e0.y*w[1] + e0.z*w[2] + e0.w*w[3];
        acc += e1.x*w[4] + e1.y*w[5] + e1.z*w[6] + e1.w*w[7];
        acc += e2.x*w[8] + e2.y*w[9] + e2.z*w[10] + e2.w*w[11];
        acc += e3.x*w[12] + e3.y*w[13] + e3.z*w[14] + e3.w*w[15];
        float g = 0.5f * acc * (1.f + erff(acc * 0.70710678118f));
        Hc[(size_t)r * HS] = __float2bfloat16(g);
    }
}

// ---------- W2 [cb][k][n] f32 -> W2T [cb][n][k] bf16 ----------
extern "C" __global__ void k_w2t(const float* __restrict__ W2, __hip_bfloat16* __restrict__ W2T) {
    __shared__ float s[64][65];
    const int k0 = blockIdx.x * 64, n0 = blockIdx.y * 64, cb = blockIdx.z;
    const int tid = threadIdx.x;
    const float* src = W2 + ((size_t)cb << 22);
    #pragma unroll
    for (int i = 0; i < 4; ++i) {                 // float4 loads
        int idx = i * 256 + tid;
        int kl = idx >> 4, n4 = (idx & 15) * 4;
        float4 v = *(const float4*)&src[(size_t)(k0 + kl) * HS + n0 + n4];
        s[kl][n4] = v.x; s[kl][n4+1] = v.y; s[kl][n4+2] = v.z; s[kl][n4+3] = v.w;
    }
    __syncthreads();
    __hip_bfloat16* dst = W2T + ((size_t)cb << 22);
    #pragma unroll
    for (int i = 0; i < 4; ++i) {                 // 4 bf16 (8B) stores per thread
        int idx = i * 256 + tid;
        int n = idx >> 4, k4 = (idx & 15) * 4;
        __align__(8) __hip_bfloat16 o[4];
        o[0] = __float2bfloat16(s[k4+0][n]); o[1] = __float2bfloat16(s[k4+1][n]);
        o[2] = __float2bfloat16(s[k4+2][n]); o[3] = __float2bfloat16(s[k4+3][n]);
        *(ushort4*)&dst[(size_t)(n0 + n) * HS + k0 + k4] = *(const ushort4*)o;
    }
}

// ---------- grouped GEMM, 256x256 tile, 8-wave phase-interleaved ----------
#define MM(m_, a_, n_, b_) acc[m_][n_] = __builtin_amdgcn_mfma_f32_16x16x32_bf16(a_, b_, acc[m_][n_], 0, 0, 0)

// one phase: 8 ds_read_b128 frags + stage-issue + barrier + 16 MFMA cluster
#define PHASE(p_, ks_, mh_, STG) do {                                          \
    const char* Ab_ = sA + (p_)*32768 + (ks_)*16384 + laneA + (mh_)*1024;      \
    const char* Bb_ = sB + (p_)*32768 + (ks_)*16384 + laneB;                   \
    s16x8 a0 = *(const s16x8*)(Ab_);                                           \
    s16x8 a1 = *(const s16x8*)(Ab_ + 256);                                     \
    s16x8 a2 = *(const s16x8*)(Ab_ + 512);                                     \
    s16x8 a3 = *(const s16x8*)(Ab_ + 768);                                     \
    s16x8 bb0 = *(const s16x8*)(Bb_);                                          \
    s16x8 bb1 = *(const s16x8*)(Bb_ + 256);                                    \
    s16x8 bb2 = *(const s16x8*)(Bb_ + 512);                                    \
    s16x8 bb3 = *(const s16x8*)(Bb_ + 768);                                    \
    STG;                                                                       \
    __builtin_amdgcn_s_barrier();                                              \
    asm volatile("s_waitcnt lgkmcnt(0)" ::: "memory");                         \
    __builtin_amdgcn_sched_barrier(0);                                         \
    __builtin_amdgcn_s_setprio(1);                                             \
    MM((mh_)*4+0, a0, 0, bb0); MM((mh_)*4+0, a0, 1, bb1);                      \
    MM((mh_)*4+0, a0, 2, bb2); MM((mh_)*4+0, a0, 3, bb3);                      \
    MM((mh_)*4+1, a1, 0, bb0); MM((mh_)*4+1, a1, 1, bb1);                      \
    MM((mh_)*4+1, a1, 2, bb2); MM((mh_)*4+1, a1, 3, bb3);                      \
    MM((mh_)*4+2, a2, 0, bb0); MM((mh_)*4+2, a2, 1, bb1);                      \
    MM((mh_)*4+2, a2, 2, bb2); MM((mh_)*4+2, a2, 3, bb3);                      \
    MM((mh_)*4+3, a3, 0, bb0); MM((mh_)*4+3, a3, 1, bb1);                      \
    MM((mh_)*4+3, a3, 2, bb2); MM((mh_)*4+3, a3, 3, bb3);                      \
    __builtin_amdgcn_s_setprio(0);                                             \
} while (0)

#define STAGE_A(q_, c47_, koff_) do {                                          \
    const unsigned short* _g = gA_t + (koff_) + (c47_) * 32;                   \
    load_lds16(_g,      sA + (q_)*32768 + (c47_)*16384 + wbase);               \
    load_lds16(_g + 16, sA + (q_)*32768 + (c47_)*16384 + wbase + 8192);        \
} while (0)
#define STAGE_B(q_, c47_, koff_) do {                                          \
    const unsigned short* _g = gB_t + (koff_) + (c47_) * 32;                   \
    load_lds16(_g,      sB + (q_)*32768 + (c47_)*16384 + wbase);               \
    load_lds16(_g + 16, sB + (q_)*32768 + (c47_)*16384 + wbase + 8192);        \
} while (0)

#define VM4 asm volatile("s_waitcnt vmcnt(4)" ::: "memory")
#define VM0 asm volatile("s_waitcnt vmcnt(0)" ::: "memory")
#define BAR __builtin_amdgcn_s_barrier()
#define NOSTG ((void)0)

extern "C" __global__ void __launch_bounds__(512, 2) k_gemm(
    const __hip_bfloat16* __restrict__ Hb, const __hip_bfloat16* __restrict__ W2Tb,
    const float* __restrict__ b2, const uint32_t* __restrict__ numT,
    const uint32_t* __restrict__ tcb, const uint32_t* __restrict__ trow,
    const uint32_t* __restrict__ tval, const uint32_t* __restrict__ perm,
    float* __restrict__ out)
{
    const int mslot = blockIdx.y;
    if (mslot >= (int)*numT) return;
    const int cb = (int)tcb[mslot];
    const int row0 = (int)trow[mslot];
    const int valid = (int)tval[mslot];
    const int n0 = blockIdx.x * BN;

    const int tid = threadIdx.x;
    const int lane = tid & 63, wave = tid >> 6;
    const int wm = wave >> 2, wn = wave & 3;

    // LDS: per operand 2 dbuf x [8 kc][256 row][8 bf16] = 64 KB; total 128 KB
    __shared__ __align__(16) char sA[65536];
    __shared__ __align__(16) char sB[65536];

    const unsigned short* H  = (const unsigned short*)Hb;
    const unsigned short* W2 = (const unsigned short*)W2Tb;

    // staging: per-thread global source (per-lane row; clamped A rows for partial tiles)
    const int trl = tid & 255;
    const int rA = trl < valid ? trl : (valid - 1);
    const unsigned short* gA_t = H  + (size_t)(row0 + rA) * HS + (tid >> 8) * 8;
    const unsigned short* gB_t = W2 + ((size_t)cb * HS + n0 + trl) * HS + (tid >> 8) * 8;
    const uint32_t wbase = (uint32_t)__builtin_amdgcn_readfirstlane((uint32_t)(wave << 10));

    // fragment read bases (byte offsets into sA/sB)
    const uint32_t laneA = ((uint32_t)(lane >> 4) << 12) + (((uint32_t)(lane & 15) + wm * 128) << 4);
    const uint32_t laneB = ((uint32_t)(lane >> 4) << 12) + (((uint32_t)(lane & 15) + wn * 64) << 4);

    f32x4 acc[8][4];
    #pragma unroll
    for (int i = 0; i < 8; ++i)
        #pragma unroll
        for (int j = 0; j < 4; ++j) acc[i][j] = (f32x4){0.f, 0.f, 0.f, 0.f};

    // prologue: stage K-tile 0 into buf0 (A03, B03, A47, B47), wait first half
    STAGE_A(0, 0, 0); STAGE_B(0, 0, 0); STAGE_A(0, 1, 0); STAGE_B(0, 1, 0);
    VM4;
    BAR;

    // steady state: at iteration entry, 4 outstanding loads = {A,B}(p, ks=1).
    // phase-2 VM4 retires them (4 newer loads queued behind) before phase 3 reads ks=1.
    #pragma unroll 2
    for (int kt = 0; kt < NKT - 1; ++kt) {
        const int p = kt & 1, q = p ^ 1;
        const int koff = (kt + 1) * BK;
        PHASE(p, 0, 0, STAGE_A(q, 0, koff));      BAR;
        PHASE(p, 0, 1, STAGE_B(q, 0, koff)); VM4; BAR;
        PHASE(p, 1, 0, STAGE_A(q, 1, koff));      BAR;
        PHASE(p, 1, 1, STAGE_B(q, 1, koff)); VM4; BAR;
    }
    // last K-tile (p=1): nothing new queued, so VM4 would NOT retire the 4
    // outstanding ks=1 loads — drain with vmcnt(0) before phase 3 reads ks=1.
    PHASE(1, 0, 0, NOSTG);      BAR;
    PHASE(1, 0, 1, NOSTG); VM0; BAR;
    PHASE(1, 1, 0, NOSTG);      BAR;
    PHASE(1, 1, 1, NOSTG);

    // epilogue: + b2, scatter rows through perm
    const float* b2k = b2 + (size_t)cb * HS;
    const int colb = n0 + wn * 64 + (lane & 15);
    float bias[4];
    #pragma unroll
    for (int nf = 0; nf < 4; ++nf) bias[nf] = b2k[colb + nf * 16];

    #pragma unroll
    for (int mf = 0; mf < 8; ++mf) {
        #pragma unroll
        for (int jj = 0; jj < 4; ++jj) {
            const int m = wm * 128 + mf * 16 + (lane >> 4) * 4 + jj;
            if (m < valid) {
                float* op = out + (size_t)perm[row0 + m] * HS;
                #pragma unroll
                for (int nf = 0; nf < 4; ++nf)
                    op[colb + nf * 16] = acc[mf][nf][jj] + bias[nf];
            }
        }
    }
}

extern "C" void kernel_launch(void* const* d_in, const int* in_sizes, int n_in,
                              void* d_out, int out_size, void* d_ws, size_t ws_size,
                              hipStream_t stream) {
    const int*   ids = (const int*)d_in[0];
    const float* emb = (const float*)d_in[1];
    const float* W1  = (const float*)d_in[2];
    const float* b1  = (const float*)d_in[3];
    const float* W2  = (const float*)d_in[4];
    const float* b2  = (const float*)d_in[5];
    float* out = (float*)d_out;

    if (ws_size < (size_t)WS_NEED) return;  // loud failure instead of corruption

    char* ws = (char*)d_ws;
    uint32_t* cur    = (uint32_t*)(ws + OFF_CUR);
    uint32_t* numT   = (uint32_t*)(ws + OFF_NT);
    uint32_t* gstart = (uint32_t*)(ws + OFF_GS);
    uint32_t* tcb    = (uint32_t*)(ws + OFF_TCB);
    uint32_t* trow   = (uint32_t*)(ws + OFF_TROW);
    uint32_t* tval   = (uint32_t*)(ws + OFF_TVAL);
    uint32_t* perm   = (uint32_t*)(ws + OFF_PERM);
    __hip_bfloat16* Hbf  = (__hip_bfloat16*)(ws + OFF_H);
    __hip_bfloat16* W2Tb = (__hip_bfloat16*)(ws + OFF_W2T);

    k_countplan<<<1, 1024, 0, stream>>>(ids, cur, numT, tcb, trow, tval, gstart);
    k_assign   <<<NTOK / 256, 256, 0, stream>>>(ids, gstart, cur, perm);
    k_w2t      <<<dim3(32, 32, 8), 256, 0, stream>>>(W2, W2Tb);
    k_hbuild   <<<dim3(MAXT, 8), 256, 0, stream>>>(ids, emb, W1, b1, numT, tcb, trow, tval, perm, Hbf);
    k_gemm     <<<dim3(HS / BN, MAXT), 512, 0, stream>>>(Hbf, W2Tb, b2, numT, tcb, trow, tval, perm, out);
}

// Round 6
// 635.233 us; speedup vs baseline: 1.0241x; 1.0241x over previous
//
#include <hip/hip_runtime.h>
#include <hip/hip_bf16.h>
#include <stdint.h>

// Problem constants
#define NUM_CB   8
#define CB_BITS  11      // id >> 11 = codebook
#define DIM      16
#define HS       2048
#define NTOK     16384

// GEMM tiling: 256x256 tile, BK=64, 8 waves (512 thr), phase-interleaved
#define BM 256
#define BN 256
#define BK 64
#define NKT (HS / BK)    // 32 K-tiles
#define MAXT 72          // sum ceil(cnt_k/256) <= 16384/256 + 8 = 72
#define GEMM_GRID (8 * MAXT)   // 576, divisible by 8 XCDs

// Workspace layout (bytes) — total 134,287,360 (known-OK)
#define OFF_CUR    0u
#define OFF_NT     64u
#define OFF_GS     128u
#define OFF_TCB    256u
#define OFF_TROW   1024u
#define OFF_TVAL   2048u
#define OFF_PERM   4096u        // 16384 x u32 -> ends 69632
#define OFF_H      69632u       // 16384*2048 bf16 = 67108864
#define OFF_W2T    67178496u    // 8*2048*2048 bf16 = 67108864
#define WS_NEED    134287360u

typedef __attribute__((ext_vector_type(8))) short s16x8;
typedef __attribute__((ext_vector_type(4))) float f32x4;

__device__ __forceinline__ void load_lds16(const void* g, const void* l) {
    __builtin_amdgcn_global_load_lds(
        (const __attribute__((address_space(1))) uint32_t*)g,
        (__attribute__((address_space(3))) uint32_t*)(void*)(uintptr_t)l, 16, 0, 0);
}

// ---------- planning ----------
extern "C" __global__ void k_countplan(const int* __restrict__ ids,
                                       uint32_t* __restrict__ cur, uint32_t* __restrict__ numT,
                                       uint32_t* __restrict__ tcb, uint32_t* __restrict__ trow,
                                       uint32_t* __restrict__ tval, uint32_t* __restrict__ gstart) {
    __shared__ uint32_t hist[NUM_CB];
    __shared__ uint32_t s_tcb[MAXT], s_trow[MAXT], s_tval[MAXT];
    __shared__ uint32_t s_gs[NUM_CB], s_nt;
    const int tid = threadIdx.x;
    if (tid < NUM_CB) { hist[tid] = 0; cur[tid] = 0; }
    __syncthreads();
    uint32_t c0=0,c1=0,c2=0,c3=0,c4=0,c5=0,c6=0,c7=0;
    const int4* v4 = (const int4*)ids;
    for (int i = tid; i < NTOK / 4; i += 1024) {
        int4 v = v4[i];
        uint32_t a = (uint32_t)v.x >> CB_BITS, b = (uint32_t)v.y >> CB_BITS;
        uint32_t cc = (uint32_t)v.z >> CB_BITS, d = (uint32_t)v.w >> CB_BITS;
        c0 += (a==0)+(b==0)+(cc==0)+(d==0);  c1 += (a==1)+(b==1)+(cc==1)+(d==1);
        c2 += (a==2)+(b==2)+(cc==2)+(d==2);  c3 += (a==3)+(b==3)+(cc==3)+(d==3);
        c4 += (a==4)+(b==4)+(cc==4)+(d==4);  c5 += (a==5)+(b==5)+(cc==5)+(d==5);
        c6 += (a==6)+(b==6)+(cc==6)+(d==6);  c7 += (a==7)+(b==7)+(cc==7)+(d==7);
    }
    #pragma unroll
    for (int off = 32; off > 0; off >>= 1) {
        c0 += __shfl_down(c0, off); c1 += __shfl_down(c1, off);
        c2 += __shfl_down(c2, off); c3 += __shfl_down(c3, off);
        c4 += __shfl_down(c4, off); c5 += __shfl_down(c5, off);
        c6 += __shfl_down(c6, off); c7 += __shfl_down(c7, off);
    }
    if ((tid & 63) == 0) {
        if (c0) atomicAdd(&hist[0], c0); if (c1) atomicAdd(&hist[1], c1);
        if (c2) atomicAdd(&hist[2], c2); if (c3) atomicAdd(&hist[3], c3);
        if (c4) atomicAdd(&hist[4], c4); if (c5) atomicAdd(&hist[5], c5);
        if (c6) atomicAdd(&hist[6], c6); if (c7) atomicAdd(&hist[7], c7);
    }
    __syncthreads();
    if (tid == 0) {
        uint32_t ps = 0, nt = 0;
        for (int k = 0; k < NUM_CB; ++k) {
            s_gs[k] = ps;
            uint32_t c = hist[k];
            uint32_t tiles = (c + BM - 1) / BM;
            for (uint32_t m = 0; m < tiles; ++m) {
                s_tcb[nt] = (uint32_t)k;
                s_trow[nt] = ps + m * BM;
                uint32_t rem = c - m * BM;
                s_tval[nt] = rem < BM ? rem : BM;
                ++nt;
            }
            ps += c;  // compact rows, no padding
        }
        s_nt = nt;
    }
    __syncthreads();
    const uint32_t nt = s_nt;
    if (tid < MAXT) {
        tcb[tid]  = (tid < (int)nt) ? s_tcb[tid] : 0u;
        trow[tid] = (tid < (int)nt) ? s_trow[tid] : 0u;
        tval[tid] = (tid < (int)nt) ? s_tval[tid] : 0u;
    }
    if (tid < NUM_CB) gstart[tid] = s_gs[tid];
    if (tid == 0) *numT = nt;
}

extern "C" __global__ void k_assign(const int* __restrict__ ids, const uint32_t* __restrict__ gstart,
                                    uint32_t* __restrict__ cur, uint32_t* __restrict__ perm) {
    __shared__ uint32_t lh[NUM_CB], lbase[NUM_CB];
    const int tid = threadIdx.x;
    const int t = blockIdx.x * 256 + tid;
    if (tid < NUM_CB) lh[tid] = 0;
    __syncthreads();
    const int cb = (uint32_t)ids[t] >> CB_BITS;
    atomicAdd(&lh[cb], 1u);
    __syncthreads();
    if (tid < NUM_CB) {
        lbase[tid] = lh[tid] ? atomicAdd(&cur[tid], lh[tid]) : 0u;
        lh[tid] = 0;
    }
    __syncthreads();
    const uint32_t r = atomicAdd(&lh[cb], 1u);
    perm[gstart[cb] + lbase[cb] + r] = (uint32_t)t;
}

// ---------- H build: 256-row tiles, grid (MAXT, 8) ----------
extern "C" __global__ void k_hbuild(const int* __restrict__ ids, const float* __restrict__ emb,
                                    const float* __restrict__ W1, const float* __restrict__ b1,
                                    const uint32_t* __restrict__ numT, const uint32_t* __restrict__ tcb,
                                    const uint32_t* __restrict__ trow, const uint32_t* __restrict__ tval,
                                    const uint32_t* __restrict__ perm, __hip_bfloat16* __restrict__ H) {
    if (blockIdx.x >= *numT) return;
    const int cb = (int)tcb[blockIdx.x];
    const int row0 = (int)trow[blockIdx.x];
    const int valid = (int)tval[blockIdx.x];
    const int col0 = blockIdx.y * 256;
    const int tid = threadIdx.x;

    __shared__ float es[BM][DIM];     // 16 KB
    __shared__ float w1s[DIM][256];   // 16 KB
    __shared__ int   rid[BM];

    rid[tid] = (tid < valid) ? ids[perm[row0 + tid]] : 0;
    __syncthreads();
    #pragma unroll
    for (int i = 0; i < 4; ++i) {
        int idx = i * 256 + tid;
        int r = idx >> 2, q = (idx & 3) * 4;
        *(float4*)&es[r][q] = *(const float4*)&emb[(size_t)rid[r] * DIM + q];
    }
    const float* W1k = W1 + (size_t)cb * DIM * HS + col0;
    #pragma unroll
    for (int i = 0; i < 4; ++i) {
        int idx = i * 256 + tid;
        int d = idx >> 6, c4 = (idx & 63) * 4;
        *(float4*)&w1s[d][c4] = *(const float4*)&W1k[(size_t)d * HS + c4];
    }
    __syncthreads();

    float w[DIM];
    #pragma unroll
    for (int d = 0; d < DIM; ++d) w[d] = w1s[d][tid];
    const float bb = b1[(size_t)cb * HS + col0 + tid];
    __hip_bfloat16* Hc = H + (size_t)row0 * HS + col0 + tid;

    for (int r = 0; r < BM; ++r) {
        if (r >= valid) break;
        const float4 e0 = *(const float4*)&es[r][0];
        const float4 e1 = *(const float4*)&es[r][4];
        const float4 e2 = *(const float4*)&es[r][8];
        const float4 e3 = *(const float4*)&es[r][12];
        float acc = bb;
        acc += e0.x*w[0] + e0.y*w[1] + e0.z*w[2] + e0.w*w[3];
        acc += e1.x*w[4] + e1.y*w[5] + e1.z*w[6] + e1.w*w[7];
        acc += e2.x*w[8] + e2.y*w[9] + e2.z*w[10] + e2.w*w[11];
        acc += e3.x*w[12] + e3.y*w[13] + e3.z*w[14] + e3.w*w[15];
        float g = 0.5f * acc * (1.f + erff(acc * 0.70710678118f));
        Hc[(size_t)r * HS] = __float2bfloat16(g);
    }
}

// ---------- W2 [cb][k][n] f32 -> W2T [cb][n][k] bf16 ----------
extern "C" __global__ void k_w2t(const float* __restrict__ W2, __hip_bfloat16* __restrict__ W2T) {
    __shared__ float s[64][65];
    const int k0 = blockIdx.x * 64, n0 = blockIdx.y * 64, cb = blockIdx.z;
    const int tid = threadIdx.x;
    const float* src = W2 + ((size_t)cb << 22);
    #pragma unroll
    for (int i = 0; i < 4; ++i) {
        int idx = i * 256 + tid;
        int kl = idx >> 4, n4 = (idx & 15) * 4;
        float4 v = *(const float4*)&src[(size_t)(k0 + kl) * HS + n0 + n4];
        s[kl][n4] = v.x; s[kl][n4+1] = v.y; s[kl][n4+2] = v.z; s[kl][n4+3] = v.w;
    }
    __syncthreads();
    __hip_bfloat16* dst = W2T + ((size_t)cb << 22);
    #pragma unroll
    for (int i = 0; i < 4; ++i) {
        int idx = i * 256 + tid;
        int n = idx >> 4, k4 = (idx & 15) * 4;
        __align__(8) __hip_bfloat16 o[4];
        o[0] = __float2bfloat16(s[k4+0][n]); o[1] = __float2bfloat16(s[k4+1][n]);
        o[2] = __float2bfloat16(s[k4+2][n]); o[3] = __float2bfloat16(s[k4+3][n]);
        *(ushort4*)&dst[(size_t)(n0 + n) * HS + k0 + k4] = *(const ushort4*)o;
    }
}

// ---------- grouped GEMM, 256x256 tile, 8-wave, XCD-swizzled, B-reg-reuse ----------
#define MM(m_, a_, n_, b_) acc[m_][n_] = __builtin_amdgcn_mfma_f32_16x16x32_bf16(a_, b_, acc[m_][n_], 0, 0, 0)

#define STAGE_A(q_, c47_, koff_) do {                                          \
    const unsigned short* _g = gA_t + (koff_) + (c47_) * 32;                   \
    load_lds16(_g,      sA + (q_)*32768 + (c47_)*16384 + wbase);               \
    load_lds16(_g + 16, sA + (q_)*32768 + (c47_)*16384 + wbase + 8192);        \
} while (0)
#define STAGE_B(q_, c47_, koff_) do {                                          \
    const unsigned short* _g = gB_t + (koff_) + (c47_) * 32;                   \
    load_lds16(_g,      sB + (q_)*32768 + (c47_)*16384 + wbase);               \
    load_lds16(_g + 16, sB + (q_)*32768 + (c47_)*16384 + wbase + 8192);        \
} while (0)

#define VM4 asm volatile("s_waitcnt vmcnt(4)" ::: "memory")
#define VM0 asm volatile("s_waitcnt vmcnt(0)" ::: "memory")
#define BAR __builtin_amdgcn_s_barrier()
#define LGK0 asm volatile("s_waitcnt lgkmcnt(0)" ::: "memory")
#define SCHB __builtin_amdgcn_sched_barrier(0)
#define NOSTG ((void)0)

// phase with B-frag loads (mh=0 rows): reads 4 B + 4 A, MFMA acc[0..3]
#define PHASE_B(p_, ks_, STG) do {                                             \
    const char* Bb_ = sB + (p_)*32768 + (ks_)*16384 + laneB;                   \
    bb0 = *(const s16x8*)(Bb_);       bb1 = *(const s16x8*)(Bb_ + 256);        \
    bb2 = *(const s16x8*)(Bb_ + 512); bb3 = *(const s16x8*)(Bb_ + 768);        \
    const char* Ab_ = sA + (p_)*32768 + (ks_)*16384 + laneA;                   \
    s16x8 a0 = *(const s16x8*)(Ab_);       s16x8 a1 = *(const s16x8*)(Ab_ + 256); \
    s16x8 a2 = *(const s16x8*)(Ab_ + 512); s16x8 a3 = *(const s16x8*)(Ab_ + 768); \
    STG;                                                                       \
    __builtin_amdgcn_s_barrier();                                              \
    LGK0; SCHB;                                                                \
    __builtin_amdgcn_s_setprio(1);                                             \
    MM(0, a0, 0, bb0); MM(0, a0, 1, bb1); MM(0, a0, 2, bb2); MM(0, a0, 3, bb3);\
    MM(1, a1, 0, bb0); MM(1, a1, 1, bb1); MM(1, a1, 2, bb2); MM(1, a1, 3, bb3);\
    MM(2, a2, 0, bb0); MM(2, a2, 1, bb1); MM(2, a2, 2, bb2); MM(2, a2, 3, bb3);\
    MM(3, a3, 0, bb0); MM(3, a3, 1, bb1); MM(3, a3, 2, bb2); MM(3, a3, 3, bb3);\
    __builtin_amdgcn_s_setprio(0);                                             \
} while (0)

// phase reusing B-frags from registers (mh=1 rows): reads 4 A, MFMA acc[4..7]
#define PHASE_R(p_, ks_, STG) do {                                             \
    const char* Ab_ = sA + (p_)*32768 + (ks_)*16384 + laneA + 1024;            \
    s16x8 a0 = *(const s16x8*)(Ab_);       s16x8 a1 = *(const s16x8*)(Ab_ + 256); \
    s16x8 a2 = *(const s16x8*)(Ab_ + 512); s16x8 a3 = *(const s16x8*)(Ab_ + 768); \
    STG;                                                                       \
    __builtin_amdgcn_s_barrier();                                              \
    LGK0; SCHB;                                                                \
    __builtin_amdgcn_s_setprio(1);                                             \
    MM(4, a0, 0, bb0); MM(4, a0, 1, bb1); MM(4, a0, 2, bb2); MM(4, a0, 3, bb3);\
    MM(5, a1, 0, bb0); MM(5, a1, 1, bb1); MM(5, a1, 2, bb2); MM(5, a1, 3, bb3);\
    MM(6, a2, 0, bb0); MM(6, a2, 1, bb1); MM(6, a2, 2, bb2); MM(6, a2, 3, bb3);\
    MM(7, a3, 0, bb0); MM(7, a3, 1, bb1); MM(7, a3, 2, bb2); MM(7, a3, 3, bb3);\
    __builtin_amdgcn_s_setprio(0);                                             \
} while (0)

extern "C" __global__ void __launch_bounds__(512, 2) k_gemm(
    const __hip_bfloat16* __restrict__ Hb, const __hip_bfloat16* __restrict__ W2Tb,
    const float* __restrict__ b2, const uint32_t* __restrict__ numT,
    const uint32_t* __restrict__ tcb, const uint32_t* __restrict__ trow,
    const uint32_t* __restrict__ tval, const uint32_t* __restrict__ perm,
    float* __restrict__ out)
{
    // XCD-aware swizzle: consecutive work on one XCD shares the A-tile (mslot)
    // dispatch: xcd = blockIdx.x % 8; give each XCD a contiguous wg chunk.
    const int wg = (int)(blockIdx.x & 7) * (GEMM_GRID / 8) + (int)(blockIdx.x >> 3);
    const int mslot = wg >> 3;
    const int nb = wg & 7;
    if (mslot >= (int)*numT) return;
    const int cb = (int)tcb[mslot];
    const int row0 = (int)trow[mslot];
    const int valid = (int)tval[mslot];
    const int n0 = nb * BN;

    const int tid = threadIdx.x;
    const int lane = tid & 63, wave = tid >> 6;
    const int wm = wave >> 2, wn = wave & 3;

    // LDS: per operand 2 dbuf x [8 kc][256 row][8 bf16] = 64 KB; total 128 KB
    __shared__ __align__(16) char sA[65536];
    __shared__ __align__(16) char sB[65536];

    const unsigned short* H  = (const unsigned short*)Hb;
    const unsigned short* W2 = (const unsigned short*)W2Tb;

    const int trl = tid & 255;
    const int rA = trl < valid ? trl : (valid - 1);
    const unsigned short* gA_t = H  + (size_t)(row0 + rA) * HS + (tid >> 8) * 8;
    const unsigned short* gB_t = W2 + ((size_t)cb * HS + n0 + trl) * HS + (tid >> 8) * 8;
    const uint32_t wbase = (uint32_t)__builtin_amdgcn_readfirstlane((uint32_t)(wave << 10));

    const uint32_t laneA = ((uint32_t)(lane >> 4) << 12) + (((uint32_t)(lane & 15) + wm * 128) << 4);
    const uint32_t laneB = ((uint32_t)(lane >> 4) << 12) + (((uint32_t)(lane & 15) + wn * 64) << 4);

    f32x4 acc[8][4];
    #pragma unroll
    for (int i = 0; i < 8; ++i)
        #pragma unroll
        for (int j = 0; j < 4; ++j) acc[i][j] = (f32x4){0.f, 0.f, 0.f, 0.f};

    s16x8 bb0, bb1, bb2, bb3;

    // prologue: stage K-tile 0 into buf0
    STAGE_A(0, 0, 0); STAGE_B(0, 0, 0); STAGE_A(0, 1, 0); STAGE_B(0, 1, 0);
    VM4;
    BAR;

    // steady state: entry has 4 outstanding = {A,B}(p, ks=1); ph1's VM4 retires
    // them (4 newer queued behind) before ph2 reads ks=1. Verified R3/R5.
    for (int kt = 0; kt < NKT - 1; ++kt) {
        const int p = kt & 1, q = p ^ 1;
        const int koff = (kt + 1) * BK;
        PHASE_B(p, 0, STAGE_A(q, 0, koff));      BAR;
        PHASE_R(p, 0, STAGE_B(q, 0, koff)); VM4; BAR;
        PHASE_B(p, 1, STAGE_A(q, 1, koff));      BAR;
        PHASE_R(p, 1, STAGE_B(q, 1, koff)); VM4; BAR;
    }
    // last K-tile (p=1): drain remaining ks=1 loads with vmcnt(0) before ph2.
    PHASE_B(1, 0, NOSTG);      BAR;
    PHASE_R(1, 0, NOSTG); VM0; BAR;
    PHASE_B(1, 1, NOSTG);      BAR;
    PHASE_R(1, 1, NOSTG);

    // epilogue: + b2, scatter rows through perm
    const float* b2k = b2 + (size_t)cb * HS;
    const int colb = n0 + wn * 64 + (lane & 15);
    float bias[4];
    #pragma unroll
    for (int nf = 0; nf < 4; ++nf) bias[nf] = b2k[colb + nf * 16];

    #pragma unroll
    for (int mf = 0; mf < 8; ++mf) {
        #pragma unroll
        for (int jj = 0; jj < 4; ++jj) {
            const int m = wm * 128 + mf * 16 + (lane >> 4) * 4 + jj;
            if (m < valid) {
                float* op = out + (size_t)perm[row0 + m] * HS;
                #pragma unroll
                for (int nf = 0; nf < 4; ++nf)
                    op[colb + nf * 16] = acc[mf][nf][jj] + bias[nf];
            }
        }
    }
}

extern "C" void kernel_launch(void* const* d_in, const int* in_sizes, int n_in,
                              void* d_out, int out_size, void* d_ws, size_t ws_size,
                              hipStream_t stream) {
    const int*   ids = (const int*)d_in[0];
    const float* emb = (const float*)d_in[1];
    const float* W1  = (const float*)d_in[2];
    const float* b1  = (const float*)d_in[3];
    const float* W2  = (const float*)d_in[4];
    const float* b2  = (const float*)d_in[5];
    float* out = (float*)d_out;

    if (ws_size < (size_t)WS_NEED) return;  // loud failure instead of corruption

    char* ws = (char*)d_ws;
    uint32_t* cur    = (uint32_t*)(ws + OFF_CUR);
    uint32_t* numT   = (uint32_t*)(ws + OFF_NT);
    uint32_t* gstart = (uint32_t*)(ws + OFF_GS);
    uint32_t* tcb    = (uint32_t*)(ws + OFF_TCB);
    uint32_t* trow   = (uint32_t*)(ws + OFF_TROW);
    uint32_t* tval   = (uint32_t*)(ws + OFF_TVAL);
    uint32_t* perm   = (uint32_t*)(ws + OFF_PERM);
    __hip_bfloat16* Hbf  = (__hip_bfloat16*)(ws + OFF_H);
    __hip_bfloat16* W2Tb = (__hip_bfloat16*)(ws + OFF_W2T);

    k_countplan<<<1, 1024, 0, stream>>>(ids, cur, numT, tcb, trow, tval, gstart);
    k_assign   <<<NTOK / 256, 256, 0, stream>>>(ids, gstart, cur, perm);
    k_w2t      <<<dim3(32, 32, 8), 256, 0, stream>>>(W2, W2Tb);
    k_hbuild   <<<dim3(MAXT, 8), 256, 0, stream>>>(ids, emb, W1, b1, numT, tcb, trow, tval, perm, Hbf);
    k_gemm     <<<GEMM_GRID, 512, 0, stream>>>(Hbf, W2Tb, b2, numT, tcb, trow, tval, perm, out);
}